// Round 6
// baseline (352.212 us; speedup 1.0000x reference)
//
#include <hip/hip_runtime.h>
#include <hip/hip_bf16.h>

#define N_NODES 50000
#define N_EDGES 600000
#define IN_DIM 128
#define HID 256
#define OUT_DIM 3

#define M_PAD 50048  // 391 blocks * 128 rows

#define SCAN_B 256
#define SCAN_NB ((N_NODES + SCAN_B - 1) / SCAN_B)  // 196

typedef __bf16 bf16x8 __attribute__((ext_vector_type(8)));
typedef float f32x4 __attribute__((ext_vector_type(4)));

static __device__ __forceinline__ unsigned short f2b(float f) {
    union { float f; unsigned u; } u; u.f = f;
    unsigned r = u.u + 0x7fffu + ((u.u >> 16) & 1u);  // round-to-nearest-even
    return (unsigned short)(r >> 16);
}
static __device__ __forceinline__ float b2f(unsigned short b) {
    union { unsigned u; float f; } u; u.u = ((unsigned)b) << 16;
    return u.f;
}

// ---------------- CSR build ----------------

__global__ void count_deg_kernel(const int* __restrict__ dst, int* __restrict__ counts) {
    int e = blockIdx.x * blockDim.x + threadIdx.x;
    if (e < N_EDGES) atomicAdd(&counts[dst[e]], 1);
}

__global__ __launch_bounds__(256) void block_sum_kernel(const int* __restrict__ counts,
                                                        int* __restrict__ partial) {
    int node = blockIdx.x * SCAN_B + threadIdx.x;
    int v = (node < N_NODES) ? counts[node] : 0;
#pragma unroll
    for (int off = 32; off > 0; off >>= 1) v += __shfl_down(v, off);
    __shared__ int ws[4];
    if ((threadIdx.x & 63) == 0) ws[threadIdx.x >> 6] = v;
    __syncthreads();
    if (threadIdx.x == 0) partial[blockIdx.x] = ws[0] + ws[1] + ws[2] + ws[3];
}

__global__ __launch_bounds__(256) void scan_partial_kernel(int* __restrict__ partial) {
    __shared__ int s[SCAN_B];
    int t = threadIdx.x;
    int v = (t < SCAN_NB) ? partial[t] : 0;
    s[t] = v;
    __syncthreads();
    for (int off = 1; off < SCAN_B; off <<= 1) {
        int u = (t >= off) ? s[t - off] : 0;
        __syncthreads();
        s[t] += u;
        __syncthreads();
    }
    if (t < SCAN_NB) partial[t] = s[t] - v;  // exclusive
}

__global__ __launch_bounds__(256) void write_rowptr_kernel(const int* __restrict__ counts,
                                                           const int* __restrict__ partial,
                                                           int* __restrict__ row_ptr) {
    __shared__ int s[SCAN_B];
    int t = threadIdx.x;
    int node = blockIdx.x * SCAN_B + t;
    int v = (node < N_NODES) ? counts[node] : 0;
    s[t] = v;
    __syncthreads();
    for (int off = 1; off < SCAN_B; off <<= 1) {
        int u = (t >= off) ? s[t - off] : 0;
        __syncthreads();
        s[t] += u;
        __syncthreads();
    }
    if (node < N_NODES) row_ptr[node] = partial[blockIdx.x] + s[t] - v;
    if (node == 0) row_ptr[N_NODES] = N_EDGES;
}

__global__ void fill_csr_kernel(const int* __restrict__ src, const int* __restrict__ dst,
                                const int* __restrict__ row_ptr, int* __restrict__ cursor,
                                int* __restrict__ csr_src) {
    int e = blockIdx.x * blockDim.x + threadIdx.x;
    if (e < N_EDGES) {
        int d = dst[e];
        int pos = atomicAdd(&cursor[d], 1);
        csr_src[row_ptr[d] + pos] = src[e];
    }
}

// ---------------- casts ----------------

__global__ void cast_f2b_kernel(const float* __restrict__ in, unsigned short* __restrict__ out, int n) {
    int i = blockIdx.x * blockDim.x + threadIdx.x;
    if (i * 4 < n) {
        float4 v = ((const float4*)in)[i];
        ushort4 o;
        o.x = f2b(v.x); o.y = f2b(v.y); o.z = f2b(v.z); o.w = f2b(v.w);
        ((ushort4*)out)[i] = o;
    }
}

// all four weight transposes in one launch
__global__ void tcast4_kernel(const float* __restrict__ W1l, const float* __restrict__ W1r,
                              const float* __restrict__ W2l, const float* __restrict__ W2r,
                              unsigned short* __restrict__ W1lt, unsigned short* __restrict__ W1rt,
                              unsigned short* __restrict__ W2lt, unsigned short* __restrict__ W2rt) {
    int i = blockIdx.x * blockDim.x + threadIdx.x;
    const float* in; unsigned short* out; int K, base;
    if (i < 32768)        { in = W1l; out = W1lt; K = IN_DIM; base = 0; }
    else if (i < 65536)   { in = W1r; out = W1rt; K = IN_DIM; base = 32768; }
    else if (i < 131072)  { in = W2l; out = W2lt; K = HID;    base = 65536; }
    else if (i < 196608)  { in = W2r; out = W2rt; K = HID;    base = 131072; }
    else return;
    int j = i - base;
    int k = j >> 8;              // N == 256
    int n = j & 255;
    out[(size_t)n * K + k] = f2b(in[j]);
}

// out[m][c] = bh[c]
__global__ void init_out_kernel(const float* __restrict__ bh, float* __restrict__ out) {
    int i = blockIdx.x * blockDim.x + threadIdx.x;
    if (i < N_NODES * 3) out[i] = bh[i % 3];
}

// ---------------- mean aggregation: multi-edge uint4 loads, fp32 acc ----------------

static __device__ __forceinline__ void addv(float* acc, uint4 v) {
    acc[0] += b2f((unsigned short)(v.x & 0xffff));
    acc[1] += b2f((unsigned short)(v.x >> 16));
    acc[2] += b2f((unsigned short)(v.y & 0xffff));
    acc[3] += b2f((unsigned short)(v.y >> 16));
    acc[4] += b2f((unsigned short)(v.z & 0xffff));
    acc[5] += b2f((unsigned short)(v.z >> 16));
    acc[6] += b2f((unsigned short)(v.w & 0xffff));
    acc[7] += b2f((unsigned short)(v.w >> 16));
}

static __device__ __forceinline__ uint4 pack8(const float* a) {
    uint4 pk;
    pk.x = (unsigned)f2b(a[0]) | ((unsigned)f2b(a[1]) << 16);
    pk.y = (unsigned)f2b(a[2]) | ((unsigned)f2b(a[3]) << 16);
    pk.z = (unsigned)f2b(a[4]) | ((unsigned)f2b(a[5]) << 16);
    pk.w = (unsigned)f2b(a[6]) | ((unsigned)f2b(a[7]) << 16);
    return pk;
}

// D=256: row = 512B = 32 lanes x 16B -> 2 edges per wave-load, 4 edges in flight
__global__ __launch_bounds__(256) void agg_mean256_kernel(const unsigned short* __restrict__ feat,
                                                          const int* __restrict__ row_ptr,
                                                          const int* __restrict__ csr_src,
                                                          unsigned short* __restrict__ out) {
    int node = blockIdx.x * 4 + (threadIdx.x >> 6);
    if (node >= N_NODES) return;
    int lane = threadIdx.x & 63;
    int half = lane >> 5, lh = lane & 31;
    const uint4* f4 = (const uint4*)feat;  // row stride 32 uint4
    float acc[8];
#pragma unroll
    for (int j = 0; j < 8; j++) acc[j] = 0.f;
    int beg = row_ptr[node], end = row_ptr[node + 1];
    int i = beg;
    for (; i + 4 <= end; i += 4) {
        int sA = csr_src[i + half];
        int sB = csr_src[i + 2 + half];
        uint4 vA = f4[(size_t)sA * 32 + lh];
        uint4 vB = f4[(size_t)sB * 32 + lh];
        addv(acc, vA);
        addv(acc, vB);
    }
    if (i + 2 <= end) {
        int s = csr_src[i + half];
        addv(acc, f4[(size_t)s * 32 + lh]);
        i += 2;
    }
    if (i < end && half == 0) {
        int s = csr_src[i];
        addv(acc, f4[(size_t)s * 32 + lh]);
    }
    float inv = (end > beg) ? 1.0f / (float)(end - beg) : 0.0f;
#pragma unroll
    for (int j = 0; j < 8; j++) {
        acc[j] += __shfl_xor(acc[j], 32);
        acc[j] *= inv;
    }
    if (half == 0) ((uint4*)(out + (size_t)node * 256))[lh] = pack8(acc);
}

// D=128: row = 256B = 16 lanes x 16B -> 4 edges per wave-load, 8 edges in flight
__global__ __launch_bounds__(256) void agg_mean128_kernel(const unsigned short* __restrict__ feat,
                                                          const int* __restrict__ row_ptr,
                                                          const int* __restrict__ csr_src,
                                                          unsigned short* __restrict__ out) {
    int node = blockIdx.x * 4 + (threadIdx.x >> 6);
    if (node >= N_NODES) return;
    int lane = threadIdx.x & 63;
    int q = lane >> 4, lq = lane & 15;
    const uint4* f4 = (const uint4*)feat;  // row stride 16 uint4
    float acc[8];
#pragma unroll
    for (int j = 0; j < 8; j++) acc[j] = 0.f;
    int beg = row_ptr[node], end = row_ptr[node + 1];
    int i = beg;
    for (; i + 8 <= end; i += 8) {
        int sA = csr_src[i + q];
        int sB = csr_src[i + 4 + q];
        uint4 vA = f4[(size_t)sA * 16 + lq];
        uint4 vB = f4[(size_t)sB * 16 + lq];
        addv(acc, vA);
        addv(acc, vB);
    }
    if (i + 4 <= end) {
        int s = csr_src[i + q];
        addv(acc, f4[(size_t)s * 16 + lq]);
        i += 4;
    }
    int rem = end - i;
    if (q < rem) {
        int s = csr_src[i + q];
        addv(acc, f4[(size_t)s * 16 + lq]);
    }
    float inv = (end > beg) ? 1.0f / (float)(end - beg) : 0.0f;
#pragma unroll
    for (int j = 0; j < 8; j++) {
        acc[j] += __shfl_xor(acc[j], 32);
        acc[j] += __shfl_xor(acc[j], 16);
        acc[j] *= inv;
    }
    if (q == 0) ((uint4*)(out + (size_t)node * 128))[lq] = pack8(acc);
}

// ---------------- barrier-free register GEMM ----------------
// Each wave computes a 32(M) x 64(N) tile. A-frags from global (L3-backed, coalesced
// 16 rows x 64B per load); B-frags from the L1/L2-resident transposed weights [N][K].
// No LDS, no __syncthreads. A panels padded to M_PAD rows (reads unguarded).

template <int K>
static __device__ __forceinline__ void gemm_wave(const unsigned short* __restrict__ A,
                                                 const unsigned short* __restrict__ Wt,
                                                 int arow, int n0, int lr, int quad,
                                                 f32x4 (&acc)[2][4]) {
#pragma unroll
    for (int ks = 0; ks < K / 32; ks++) {
        const int koff = ks * 32 + quad * 8;
        bf16x8 a[2], b[4];
#pragma unroll
        for (int mt = 0; mt < 2; mt++)
            a[mt] = *(const bf16x8*)(A + (size_t)(arow + mt * 16 + lr) * K + koff);
#pragma unroll
        for (int nt = 0; nt < 4; nt++)
            b[nt] = *(const bf16x8*)(Wt + (size_t)(n0 + nt * 16 + lr) * K + koff);
#pragma unroll
        for (int mt = 0; mt < 2; mt++)
#pragma unroll
            for (int nt = 0; nt < 4; nt++)
                acc[mt][nt] = __builtin_amdgcn_mfma_f32_16x16x32_bf16(a[mt], b[nt], acc[mt][nt], 0, 0, 0);
    }
}

// layer 1: out = relu(A0@W0 + A1@W1 + bias), bf16 out [M][HID]
template <int K>
__global__ __launch_bounds__(256, 4) void gemm_reg_kernel(
    const unsigned short* __restrict__ A0, const unsigned short* __restrict__ W0t,
    const unsigned short* __restrict__ A1, const unsigned short* __restrict__ W1t,
    const float* __restrict__ bias, unsigned short* __restrict__ out, int M) {
    const int t = threadIdx.x;
    const int w = t >> 6, l = t & 63;
    const int quad = l >> 4, lr = l & 15;
    const int arow = blockIdx.x * 128 + w * 32;
    const int n0 = blockIdx.y * 64;

    f32x4 acc[2][4];
    const f32x4 zero = {0.f, 0.f, 0.f, 0.f};
#pragma unroll
    for (int mt = 0; mt < 2; mt++)
#pragma unroll
        for (int nt = 0; nt < 4; nt++) acc[mt][nt] = zero;

    float bias_r[4];
#pragma unroll
    for (int nt = 0; nt < 4; nt++) bias_r[nt] = bias[n0 + nt * 16 + lr];

    gemm_wave<K>(A0, W0t, arow, n0, lr, quad, acc);
    gemm_wave<K>(A1, W1t, arow, n0, lr, quad, acc);

#pragma unroll
    for (int mt = 0; mt < 2; mt++)
#pragma unroll
        for (int r = 0; r < 4; r++) {
            int gm = arow + mt * 16 + quad * 4 + r;
            if (gm >= M) continue;
            unsigned short* orow = out + (size_t)gm * HID;
#pragma unroll
            for (int nt = 0; nt < 4; nt++) {
                float v = fmaxf(acc[mt][nt][r] + bias_r[nt], 0.f);
                orow[n0 + nt * 16 + lr] = f2b(v);
            }
        }
}

// layer 2 + head: out += sum_n relu(gemm)*Wh  (out pre-init to bh)
template <int K>
__global__ __launch_bounds__(256, 4) void gemm_reg_head_kernel(
    const unsigned short* __restrict__ A0, const unsigned short* __restrict__ W0t,
    const unsigned short* __restrict__ A1, const unsigned short* __restrict__ W1t,
    const float* __restrict__ bias, const float* __restrict__ Wh,
    float* __restrict__ out, int M) {
    const int t = threadIdx.x;
    const int w = t >> 6, l = t & 63;
    const int quad = l >> 4, lr = l & 15;
    const int arow = blockIdx.x * 128 + w * 32;
    const int n0 = blockIdx.y * 64;

    f32x4 acc[2][4];
    const f32x4 zero = {0.f, 0.f, 0.f, 0.f};
#pragma unroll
    for (int mt = 0; mt < 2; mt++)
#pragma unroll
        for (int nt = 0; nt < 4; nt++) acc[mt][nt] = zero;

    float bias_r[4];
    float wh_r[4][3];
#pragma unroll
    for (int nt = 0; nt < 4; nt++) {
        int gn = n0 + nt * 16 + lr;
        bias_r[nt] = bias[gn];
        wh_r[nt][0] = Wh[gn * 3 + 0];
        wh_r[nt][1] = Wh[gn * 3 + 1];
        wh_r[nt][2] = Wh[gn * 3 + 2];
    }

    gemm_wave<K>(A0, W0t, arow, n0, lr, quad, acc);
    gemm_wave<K>(A1, W1t, arow, n0, lr, quad, acc);

#pragma unroll
    for (int mt = 0; mt < 2; mt++)
#pragma unroll
        for (int r = 0; r < 4; r++) {
            int gm = arow + mt * 16 + quad * 4 + r;
            float p0 = 0.f, p1 = 0.f, p2 = 0.f;
#pragma unroll
            for (int nt = 0; nt < 4; nt++) {
                float v = fmaxf(acc[mt][nt][r] + bias_r[nt], 0.f);
                p0 += v * wh_r[nt][0];
                p1 += v * wh_r[nt][1];
                p2 += v * wh_r[nt][2];
            }
#pragma unroll
            for (int off = 1; off < 16; off <<= 1) {
                p0 += __shfl_xor(p0, off);
                p1 += __shfl_xor(p1, off);
                p2 += __shfl_xor(p2, off);
            }
            if (lr == 0 && gm < M) {
                atomicAdd(&out[(size_t)gm * 3 + 0], p0);
                atomicAdd(&out[(size_t)gm * 3 + 1], p1);
                atomicAdd(&out[(size_t)gm * 3 + 2], p2);
            }
        }
}

// ---------------- launch ----------------

extern "C" void kernel_launch(void* const* d_in, const int* in_sizes, int n_in,
                              void* d_out, int out_size, void* d_ws, size_t ws_size,
                              hipStream_t stream) {
    const float* x   = (const float*)d_in[0];
    const int*   ei  = (const int*)d_in[1];
    const int*   src = ei;
    const int*   dst = ei + N_EDGES;
    const float* W1l = (const float*)d_in[2];
    const float* b1  = (const float*)d_in[3];
    const float* W1r = (const float*)d_in[4];
    const float* W2l = (const float*)d_in[5];
    const float* b2  = (const float*)d_in[6];
    const float* W2r = (const float*)d_in[7];
    const float* Wh  = (const float*)d_in[8];
    const float* bh  = (const float*)d_in[9];
    float* out = (float*)d_out;

    char* ws = (char*)d_ws;
    size_t off = 0;
    auto alloc = [&](size_t bytes) -> void* {
        void* p = ws + off;
        off = (off + bytes + 255) & ~(size_t)255;
        return p;
    };
    int* counts   = (int*)alloc((size_t)N_NODES * 4);
    int* row_ptr  = (int*)alloc((size_t)(N_NODES + 1) * 4);
    int* cursor   = (int*)alloc((size_t)N_NODES * 4);
    int* partial  = (int*)alloc((size_t)SCAN_NB * 4);
    int* csr_src  = (int*)alloc((size_t)N_EDGES * 4);
    unsigned short* xb   = (unsigned short*)alloc((size_t)M_PAD * IN_DIM * 2);
    unsigned short* agg  = (unsigned short*)alloc((size_t)M_PAD * HID * 2);
    unsigned short* h1   = (unsigned short*)alloc((size_t)M_PAD * HID * 2);
    unsigned short* W1lt = (unsigned short*)alloc((size_t)IN_DIM * HID * 2);
    unsigned short* W1rt = (unsigned short*)alloc((size_t)IN_DIM * HID * 2);
    unsigned short* W2lt = (unsigned short*)alloc((size_t)HID * HID * 2);
    unsigned short* W2rt = (unsigned short*)alloc((size_t)HID * HID * 2);

    hipMemsetAsync(counts, 0, (size_t)N_NODES * 4, stream);
    hipMemsetAsync(cursor, 0, (size_t)N_NODES * 4, stream);

    const int eblocks = (N_EDGES + 255) / 256;
    count_deg_kernel<<<eblocks, 256, 0, stream>>>(dst, counts);
    block_sum_kernel<<<SCAN_NB, SCAN_B, 0, stream>>>(counts, partial);
    scan_partial_kernel<<<1, SCAN_B, 0, stream>>>(partial);
    write_rowptr_kernel<<<SCAN_NB, SCAN_B, 0, stream>>>(counts, partial, row_ptr);
    fill_csr_kernel<<<eblocks, 256, 0, stream>>>(src, dst, row_ptr, cursor, csr_src);

    // casts (independent of CSR)
    {
        int n = N_NODES * IN_DIM;
        cast_f2b_kernel<<<(n / 4 + 255) / 256, 256, 0, stream>>>(x, xb, n);
        tcast4_kernel<<<(196608 + 255) / 256, 256, 0, stream>>>(W1l, W1r, W2l, W2r,
                                                                W1lt, W1rt, W2lt, W2rt);
        init_out_kernel<<<(N_NODES * 3 + 255) / 256, 256, 0, stream>>>(bh, out);
    }

    const int nblocks4 = (N_NODES + 3) / 4;
    dim3 gg((N_NODES + 127) / 128, HID / 64);  // 391 x 4

    // layer 1
    agg_mean128_kernel<<<nblocks4, 256, 0, stream>>>(xb, row_ptr, csr_src, agg);
    gemm_reg_kernel<IN_DIM><<<gg, 256, 0, stream>>>(agg, W1lt, xb, W1rt, b1, h1, N_NODES);

    // layer 2 + head fused
    agg_mean256_kernel<<<nblocks4, 256, 0, stream>>>(h1, row_ptr, csr_src, agg);
    gemm_reg_head_kernel<HID><<<gg, 256, 0, stream>>>(agg, W2lt, h1, W2rt, b2, Wh, out, N_NODES);
}

// Round 7
// 289.790 us; speedup vs baseline: 1.2154x; 1.2154x over previous
//
#include <hip/hip_runtime.h>
#include <hip/hip_bf16.h>

#define N_NODES 50000
#define N_EDGES 600000
#define IN_DIM 128
#define HID 256
#define OUT_DIM 3

#define M_PAD 50048  // 391 blocks * 128 rows

#define SCAN_B 256
#define SCAN_NB ((N_NODES + SCAN_B - 1) / SCAN_B)  // 196

typedef __bf16 bf16x8 __attribute__((ext_vector_type(8)));
typedef float f32x4 __attribute__((ext_vector_type(4)));

static __device__ __forceinline__ unsigned short f2b(float f) {
    union { float f; unsigned u; } u; u.f = f;
    unsigned r = u.u + 0x7fffu + ((u.u >> 16) & 1u);  // round-to-nearest-even
    return (unsigned short)(r >> 16);
}
static __device__ __forceinline__ float b2f(unsigned short b) {
    union { unsigned u; float f; } u; u.u = ((unsigned)b) << 16;
    return u.f;
}

// ---------------- CSR build ----------------

__global__ void count_deg_kernel(const int* __restrict__ dst, int* __restrict__ counts) {
    int e = blockIdx.x * blockDim.x + threadIdx.x;
    if (e < N_EDGES) atomicAdd(&counts[dst[e]], 1);
}

__global__ __launch_bounds__(256) void block_sum_kernel(const int* __restrict__ counts,
                                                        int* __restrict__ partial) {
    int node = blockIdx.x * SCAN_B + threadIdx.x;
    int v = (node < N_NODES) ? counts[node] : 0;
#pragma unroll
    for (int off = 32; off > 0; off >>= 1) v += __shfl_down(v, off);
    __shared__ int ws[4];
    if ((threadIdx.x & 63) == 0) ws[threadIdx.x >> 6] = v;
    __syncthreads();
    if (threadIdx.x == 0) partial[blockIdx.x] = ws[0] + ws[1] + ws[2] + ws[3];
}

__global__ __launch_bounds__(256) void scan_partial_kernel(int* __restrict__ partial) {
    __shared__ int s[SCAN_B];
    int t = threadIdx.x;
    int v = (t < SCAN_NB) ? partial[t] : 0;
    s[t] = v;
    __syncthreads();
    for (int off = 1; off < SCAN_B; off <<= 1) {
        int u = (t >= off) ? s[t - off] : 0;
        __syncthreads();
        s[t] += u;
        __syncthreads();
    }
    if (t < SCAN_NB) partial[t] = s[t] - v;  // exclusive
}

__global__ __launch_bounds__(256) void write_rowptr_kernel(const int* __restrict__ counts,
                                                           const int* __restrict__ partial,
                                                           int* __restrict__ row_ptr) {
    __shared__ int s[SCAN_B];
    int t = threadIdx.x;
    int node = blockIdx.x * SCAN_B + t;
    int v = (node < N_NODES) ? counts[node] : 0;
    s[t] = v;
    __syncthreads();
    for (int off = 1; off < SCAN_B; off <<= 1) {
        int u = (t >= off) ? s[t - off] : 0;
        __syncthreads();
        s[t] += u;
        __syncthreads();
    }
    if (node < N_NODES) row_ptr[node] = partial[blockIdx.x] + s[t] - v;
    if (node == 0) row_ptr[N_NODES] = N_EDGES;
}

__global__ void fill_csr_kernel(const int* __restrict__ src, const int* __restrict__ dst,
                                const int* __restrict__ row_ptr, int* __restrict__ cursor,
                                int* __restrict__ csr_src) {
    int e = blockIdx.x * blockDim.x + threadIdx.x;
    if (e < N_EDGES) {
        int d = dst[e];
        int pos = atomicAdd(&cursor[d], 1);
        csr_src[row_ptr[d] + pos] = src[e];
    }
}

// ---------------- casts ----------------

__global__ void cast_f2b_kernel(const float* __restrict__ in, unsigned short* __restrict__ out, int n) {
    int i = blockIdx.x * blockDim.x + threadIdx.x;
    if (i * 4 < n) {
        float4 v = ((const float4*)in)[i];
        ushort4 o;
        o.x = f2b(v.x); o.y = f2b(v.y); o.z = f2b(v.z); o.w = f2b(v.w);
        ((ushort4*)out)[i] = o;
    }
}

// all four weight transposes in one launch
__global__ void tcast4_kernel(const float* __restrict__ W1l, const float* __restrict__ W1r,
                              const float* __restrict__ W2l, const float* __restrict__ W2r,
                              unsigned short* __restrict__ W1lt, unsigned short* __restrict__ W1rt,
                              unsigned short* __restrict__ W2lt, unsigned short* __restrict__ W2rt) {
    int i = blockIdx.x * blockDim.x + threadIdx.x;
    const float* in; unsigned short* out; int K, base;
    if (i < 32768)        { in = W1l; out = W1lt; K = IN_DIM; base = 0; }
    else if (i < 65536)   { in = W1r; out = W1rt; K = IN_DIM; base = 32768; }
    else if (i < 131072)  { in = W2l; out = W2lt; K = HID;    base = 65536; }
    else if (i < 196608)  { in = W2r; out = W2rt; K = HID;    base = 131072; }
    else return;
    int j = i - base;
    int k = j >> 8;              // N == 256
    int n = j & 255;
    out[(size_t)n * K + k] = f2b(in[j]);
}

// out[m][c] = bh[c]
__global__ void init_out_kernel(const float* __restrict__ bh, float* __restrict__ out) {
    int i = blockIdx.x * blockDim.x + threadIdx.x;
    if (i < N_NODES * 3) out[i] = bh[i % 3];
}

// ---------------- mean aggregation: multi-edge uint4 loads, fp32 acc ----------------

static __device__ __forceinline__ void addv(float* acc, uint4 v) {
    acc[0] += b2f((unsigned short)(v.x & 0xffff));
    acc[1] += b2f((unsigned short)(v.x >> 16));
    acc[2] += b2f((unsigned short)(v.y & 0xffff));
    acc[3] += b2f((unsigned short)(v.y >> 16));
    acc[4] += b2f((unsigned short)(v.z & 0xffff));
    acc[5] += b2f((unsigned short)(v.z >> 16));
    acc[6] += b2f((unsigned short)(v.w & 0xffff));
    acc[7] += b2f((unsigned short)(v.w >> 16));
}

static __device__ __forceinline__ uint4 pack8(const float* a) {
    uint4 pk;
    pk.x = (unsigned)f2b(a[0]) | ((unsigned)f2b(a[1]) << 16);
    pk.y = (unsigned)f2b(a[2]) | ((unsigned)f2b(a[3]) << 16);
    pk.z = (unsigned)f2b(a[4]) | ((unsigned)f2b(a[5]) << 16);
    pk.w = (unsigned)f2b(a[6]) | ((unsigned)f2b(a[7]) << 16);
    return pk;
}

// D=256: row = 512B = 32 lanes x 16B -> 2 edges per wave-load, 4 edges in flight
__global__ __launch_bounds__(256) void agg_mean256_kernel(const unsigned short* __restrict__ feat,
                                                          const int* __restrict__ row_ptr,
                                                          const int* __restrict__ csr_src,
                                                          unsigned short* __restrict__ out) {
    int node = blockIdx.x * 4 + (threadIdx.x >> 6);
    if (node >= N_NODES) return;
    int lane = threadIdx.x & 63;
    int half = lane >> 5, lh = lane & 31;
    const uint4* f4 = (const uint4*)feat;  // row stride 32 uint4
    float acc[8];
#pragma unroll
    for (int j = 0; j < 8; j++) acc[j] = 0.f;
    int beg = row_ptr[node], end = row_ptr[node + 1];
    int i = beg;
    for (; i + 4 <= end; i += 4) {
        int sA = csr_src[i + half];
        int sB = csr_src[i + 2 + half];
        uint4 vA = f4[(size_t)sA * 32 + lh];
        uint4 vB = f4[(size_t)sB * 32 + lh];
        addv(acc, vA);
        addv(acc, vB);
    }
    if (i + 2 <= end) {
        int s = csr_src[i + half];
        addv(acc, f4[(size_t)s * 32 + lh]);
        i += 2;
    }
    if (i < end && half == 0) {
        int s = csr_src[i];
        addv(acc, f4[(size_t)s * 32 + lh]);
    }
    float inv = (end > beg) ? 1.0f / (float)(end - beg) : 0.0f;
#pragma unroll
    for (int j = 0; j < 8; j++) {
        acc[j] += __shfl_xor(acc[j], 32);
        acc[j] *= inv;
    }
    if (half == 0) ((uint4*)(out + (size_t)node * 256))[lh] = pack8(acc);
}

// D=128: row = 256B = 16 lanes x 16B -> 4 edges per wave-load, 8 edges in flight
__global__ __launch_bounds__(256) void agg_mean128_kernel(const unsigned short* __restrict__ feat,
                                                          const int* __restrict__ row_ptr,
                                                          const int* __restrict__ csr_src,
                                                          unsigned short* __restrict__ out) {
    int node = blockIdx.x * 4 + (threadIdx.x >> 6);
    if (node >= N_NODES) return;
    int lane = threadIdx.x & 63;
    int q = lane >> 4, lq = lane & 15;
    const uint4* f4 = (const uint4*)feat;  // row stride 16 uint4
    float acc[8];
#pragma unroll
    for (int j = 0; j < 8; j++) acc[j] = 0.f;
    int beg = row_ptr[node], end = row_ptr[node + 1];
    int i = beg;
    for (; i + 8 <= end; i += 8) {
        int sA = csr_src[i + q];
        int sB = csr_src[i + 4 + q];
        uint4 vA = f4[(size_t)sA * 16 + lq];
        uint4 vB = f4[(size_t)sB * 16 + lq];
        addv(acc, vA);
        addv(acc, vB);
    }
    if (i + 4 <= end) {
        int s = csr_src[i + q];
        addv(acc, f4[(size_t)s * 16 + lq]);
        i += 4;
    }
    int rem = end - i;
    if (q < rem) {
        int s = csr_src[i + q];
        addv(acc, f4[(size_t)s * 16 + lq]);
    }
    float inv = (end > beg) ? 1.0f / (float)(end - beg) : 0.0f;
#pragma unroll
    for (int j = 0; j < 8; j++) {
        acc[j] += __shfl_xor(acc[j], 32);
        acc[j] += __shfl_xor(acc[j], 16);
        acc[j] *= inv;
    }
    if (q == 0) ((uint4*)(out + (size_t)node * 128))[lq] = pack8(acc);
}

// ---------------- pipelined double-buffered MFMA GEMM ----------------
// Tile 128(M) x 128(N), BK=32, 2 phases (A0@W0 + A1@W1). VGPR staging so the
// barrier does NOT drain vmcnt (only global_load_lds forces that): loads for
// iter k+1 are issued before the MFMAs of iter k and stay in flight across the
// barrier; the ds_write's lgkm wait is the only sync. LDS layout [kb][row][8]
// (bank-balanced, 0 conflicts measured in round 5). A panels padded to M_PAD.

template <int KP>  // per-phase K: 128 (layer1) or 256 (layer2)
static __device__ __forceinline__ void gemm_pipe_loop(
    const unsigned short* __restrict__ A0, const unsigned short* __restrict__ W0t,
    const unsigned short* __restrict__ A1, const unsigned short* __restrict__ W1t,
    unsigned short* As, unsigned short* Bs,  // each 2*4096 elems
    int m0, int n0, int t, int w, int quad, int lr, f32x4 (&acc)[2][8]) {
    constexpr int KI = KP / 32;
    constexpr int NIT = 2 * KI;
    const int kb = t & 3;   // k sub-block (8 elems)
    const int r  = t >> 2;  // 0..63

    const unsigned short* Aa[2] = {A0, A1};
    const unsigned short* Wa[2] = {W0t, W1t};

    uint4 ra0, ra1, rb0, rb1;
    auto gload = [&](int it) {
        int p = it / KI;
        int k0 = (it % KI) * 32 + kb * 8;
        const unsigned short* A = Aa[p];
        const unsigned short* Wt = Wa[p];
        ra0 = *(const uint4*)(A + (size_t)(m0 + r) * KP + k0);
        ra1 = *(const uint4*)(A + (size_t)(m0 + 64 + r) * KP + k0);
        rb0 = *(const uint4*)(Wt + (size_t)(n0 + r) * KP + k0);
        rb1 = *(const uint4*)(Wt + (size_t)(n0 + 64 + r) * KP + k0);
    };
    auto wlds = [&](int buf) {
        unsigned short* pa = As + buf * 4096;
        unsigned short* pb = Bs + buf * 4096;
        *(uint4*)&pa[(kb * 128 + r) * 8] = ra0;
        *(uint4*)&pa[(kb * 128 + 64 + r) * 8] = ra1;
        *(uint4*)&pb[(kb * 128 + r) * 8] = rb0;
        *(uint4*)&pb[(kb * 128 + 64 + r) * 8] = rb1;
    };

    gload(0);
    wlds(0);
    __syncthreads();
    for (int it = 0; it < NIT; ++it) {
        if (it + 1 < NIT) gload(it + 1);  // in flight across MFMAs + barrier
        const unsigned short* pa = As + (it & 1) * 4096;
        const unsigned short* pb = Bs + (it & 1) * 4096;
        bf16x8 a[2], b[8];
        a[0] = *(const bf16x8*)&pa[(quad * 128 + w * 32 + lr) * 8];
        a[1] = *(const bf16x8*)&pa[(quad * 128 + w * 32 + 16 + lr) * 8];
#pragma unroll
        for (int nt = 0; nt < 8; nt++)
            b[nt] = *(const bf16x8*)&pb[(quad * 128 + nt * 16 + lr) * 8];
#pragma unroll
        for (int mt = 0; mt < 2; mt++)
#pragma unroll
            for (int nt = 0; nt < 8; nt++)
                acc[mt][nt] = __builtin_amdgcn_mfma_f32_16x16x32_bf16(a[mt], b[nt], acc[mt][nt], 0, 0, 0);
        if (it + 1 < NIT) {
            wlds((it + 1) & 1);  // other buffer; waits only on its own vmcnt
            __syncthreads();
        }
    }
}

// layer 1: out = relu(A0@W0 + A1@W1 + bias), bf16 out [M][HID]
template <int KP>
__global__ __launch_bounds__(256) void gemm_pipe_kernel(
    const unsigned short* __restrict__ A0, const unsigned short* __restrict__ W0t,
    const unsigned short* __restrict__ A1, const unsigned short* __restrict__ W1t,
    const float* __restrict__ bias, unsigned short* __restrict__ out, int M) {
    __shared__ __align__(16) unsigned short As[2 * 4096];
    __shared__ __align__(16) unsigned short Bs[2 * 4096];

    const int t = threadIdx.x;
    const int w = t >> 6, l = t & 63;
    const int quad = l >> 4, lr = l & 15;
    const int m0 = blockIdx.x * 128, n0 = blockIdx.y * 128;

    f32x4 acc[2][8];
    const f32x4 zero = {0.f, 0.f, 0.f, 0.f};
#pragma unroll
    for (int mt = 0; mt < 2; mt++)
#pragma unroll
        for (int nt = 0; nt < 8; nt++) acc[mt][nt] = zero;

    float bias_r[8];
#pragma unroll
    for (int nt = 0; nt < 8; nt++) bias_r[nt] = bias[n0 + nt * 16 + lr];

    gemm_pipe_loop<KP>(A0, W0t, A1, W1t, As, Bs, m0, n0, t, w, quad, lr, acc);

#pragma unroll
    for (int mt = 0; mt < 2; mt++)
#pragma unroll
        for (int r = 0; r < 4; r++) {
            int gm = m0 + w * 32 + mt * 16 + quad * 4 + r;
            if (gm >= M) continue;
            unsigned short* orow = out + (size_t)gm * HID;
#pragma unroll
            for (int nt = 0; nt < 8; nt++) {
                float v = fmaxf(acc[mt][nt][r] + bias_r[nt], 0.f);
                orow[n0 + nt * 16 + lr] = f2b(v);
            }
        }
}

// layer 2 + head: out += sum_n relu(gemm)*Wh  (out pre-init to bh)
template <int KP>
__global__ __launch_bounds__(256) void gemm_pipe_head_kernel(
    const unsigned short* __restrict__ A0, const unsigned short* __restrict__ W0t,
    const unsigned short* __restrict__ A1, const unsigned short* __restrict__ W1t,
    const float* __restrict__ bias, const float* __restrict__ Wh,
    float* __restrict__ out, int M) {
    __shared__ __align__(16) unsigned short As[2 * 4096];
    __shared__ __align__(16) unsigned short Bs[2 * 4096];

    const int t = threadIdx.x;
    const int w = t >> 6, l = t & 63;
    const int quad = l >> 4, lr = l & 15;
    const int m0 = blockIdx.x * 128, n0 = blockIdx.y * 128;

    f32x4 acc[2][8];
    const f32x4 zero = {0.f, 0.f, 0.f, 0.f};
#pragma unroll
    for (int mt = 0; mt < 2; mt++)
#pragma unroll
        for (int nt = 0; nt < 8; nt++) acc[mt][nt] = zero;

    float bias_r[8];
    float wh_r[8][3];
#pragma unroll
    for (int nt = 0; nt < 8; nt++) {
        int gn = n0 + nt * 16 + lr;
        bias_r[nt] = bias[gn];
        wh_r[nt][0] = Wh[gn * 3 + 0];
        wh_r[nt][1] = Wh[gn * 3 + 1];
        wh_r[nt][2] = Wh[gn * 3 + 2];
    }

    gemm_pipe_loop<KP>(A0, W0t, A1, W1t, As, Bs, m0, n0, t, w, quad, lr, acc);

#pragma unroll
    for (int mt = 0; mt < 2; mt++)
#pragma unroll
        for (int r = 0; r < 4; r++) {
            int gm = m0 + w * 32 + mt * 16 + quad * 4 + r;
            float p0 = 0.f, p1 = 0.f, p2 = 0.f;
#pragma unroll
            for (int nt = 0; nt < 8; nt++) {
                float v = fmaxf(acc[mt][nt][r] + bias_r[nt], 0.f);
                p0 += v * wh_r[nt][0];
                p1 += v * wh_r[nt][1];
                p2 += v * wh_r[nt][2];
            }
#pragma unroll
            for (int off = 1; off < 16; off <<= 1) {
                p0 += __shfl_xor(p0, off);
                p1 += __shfl_xor(p1, off);
                p2 += __shfl_xor(p2, off);
            }
            if (lr == 0 && gm < M) {
                atomicAdd(&out[(size_t)gm * 3 + 0], p0);
                atomicAdd(&out[(size_t)gm * 3 + 1], p1);
                atomicAdd(&out[(size_t)gm * 3 + 2], p2);
            }
        }
}

// ---------------- launch ----------------

extern "C" void kernel_launch(void* const* d_in, const int* in_sizes, int n_in,
                              void* d_out, int out_size, void* d_ws, size_t ws_size,
                              hipStream_t stream) {
    const float* x   = (const float*)d_in[0];
    const int*   ei  = (const int*)d_in[1];
    const int*   src = ei;
    const int*   dst = ei + N_EDGES;
    const float* W1l = (const float*)d_in[2];
    const float* b1  = (const float*)d_in[3];
    const float* W1r = (const float*)d_in[4];
    const float* W2l = (const float*)d_in[5];
    const float* b2  = (const float*)d_in[6];
    const float* W2r = (const float*)d_in[7];
    const float* Wh  = (const float*)d_in[8];
    const float* bh  = (const float*)d_in[9];
    float* out = (float*)d_out;

    char* ws = (char*)d_ws;
    size_t off = 0;
    auto alloc = [&](size_t bytes) -> void* {
        void* p = ws + off;
        off = (off + bytes + 255) & ~(size_t)255;
        return p;
    };
    int* counts   = (int*)alloc((size_t)N_NODES * 4);
    int* row_ptr  = (int*)alloc((size_t)(N_NODES + 1) * 4);
    int* cursor   = (int*)alloc((size_t)N_NODES * 4);
    int* partial  = (int*)alloc((size_t)SCAN_NB * 4);
    int* csr_src  = (int*)alloc((size_t)N_EDGES * 4);
    unsigned short* xb   = (unsigned short*)alloc((size_t)M_PAD * IN_DIM * 2);
    unsigned short* agg  = (unsigned short*)alloc((size_t)M_PAD * HID * 2);
    unsigned short* h1   = (unsigned short*)alloc((size_t)M_PAD * HID * 2);
    unsigned short* W1lt = (unsigned short*)alloc((size_t)IN_DIM * HID * 2);
    unsigned short* W1rt = (unsigned short*)alloc((size_t)IN_DIM * HID * 2);
    unsigned short* W2lt = (unsigned short*)alloc((size_t)HID * HID * 2);
    unsigned short* W2rt = (unsigned short*)alloc((size_t)HID * HID * 2);

    hipMemsetAsync(counts, 0, (size_t)N_NODES * 4, stream);
    hipMemsetAsync(cursor, 0, (size_t)N_NODES * 4, stream);

    const int eblocks = (N_EDGES + 255) / 256;
    count_deg_kernel<<<eblocks, 256, 0, stream>>>(dst, counts);
    block_sum_kernel<<<SCAN_NB, SCAN_B, 0, stream>>>(counts, partial);
    scan_partial_kernel<<<1, SCAN_B, 0, stream>>>(partial);
    write_rowptr_kernel<<<SCAN_NB, SCAN_B, 0, stream>>>(counts, partial, row_ptr);
    fill_csr_kernel<<<eblocks, 256, 0, stream>>>(src, dst, row_ptr, cursor, csr_src);

    // casts (independent of CSR)
    {
        int n = N_NODES * IN_DIM;
        cast_f2b_kernel<<<(n / 4 + 255) / 256, 256, 0, stream>>>(x, xb, n);
        tcast4_kernel<<<(196608 + 255) / 256, 256, 0, stream>>>(W1l, W1r, W2l, W2r,
                                                                W1lt, W1rt, W2lt, W2rt);
        init_out_kernel<<<(N_NODES * 3 + 255) / 256, 256, 0, stream>>>(bh, out);
    }

    const int nblocks4 = (N_NODES + 3) / 4;
    dim3 gg(M_PAD / 128, HID / 128);  // 391 x 2

    // layer 1
    agg_mean128_kernel<<<nblocks4, 256, 0, stream>>>(xb, row_ptr, csr_src, agg);
    gemm_pipe_kernel<IN_DIM><<<gg, 256, 0, stream>>>(agg, W1lt, xb, W1rt, b1, h1, N_NODES);

    // layer 2 + head fused
    agg_mean256_kernel<<<nblocks4, 256, 0, stream>>>(h1, row_ptr, csr_src, agg);
    gemm_pipe_head_kernel<HID><<<gg, 256, 0, stream>>>(agg, W2lt, h1, W2rt, b2, Wh, out, N_NODES);
}